// Round 5
// baseline (7507.355 us; speedup 1.0000x reference)
//
#include <hip/hip_runtime.h>
#include <hip/hip_cooperative_groups.h>

namespace cg = cooperative_groups;

#define NH   4096
#define OBS  512
#define TPTS 64
#define LAT2 128
#define COMB (OBS + NH)

// ============================================================================
// Persistent cooperative RK4 with Wf fully register-resident.
// 256 blocks x 1024 threads, 1 block/CU. Block b owns rows b*16..b*16+15.
// Wave w = (wr,wc): wr=w>>2 row-group (4 rows), wc=w&3 column-quarter (1024).
// Lane l holds wreg[i][j] = Wf[rowbase+wr*4+i][wc*1024 + j*256 + l*4 .. +3]
//   -> 16 float4 = 64 VGPRs of weights, all statically indexed.
// ============================================================================
__global__ __launch_bounds__(1024, 4) void ode_resident(
    const float* __restrict__ Wf, const float* __restrict__ bf,
    const float* __restrict__ t,
    float* hA, float* hB, float* k1g, float* k2g, float* k3g)
{
    cg::grid_group grid = cg::this_grid();
    __shared__ float vlds[NH];        // staged input vector (16 KB)
    __shared__ float pLDS[16][4];     // cross-wave partials [row][wc]
    __shared__ float tsh[TPTS];

    const int tid = threadIdx.x;
    const int l   = tid & 63;
    const int w   = tid >> 6;
    const int wr  = w >> 2;
    const int wc  = w & 3;
    const int rowbase = blockIdx.x * 16;

    // ---- one-time: weights into VGPRs (coalesced per (i,j): 64 lanes x 16B) --
    float4 wreg[4][4];
    #pragma unroll
    for (int i = 0; i < 4; ++i) {
        const float* wrow = Wf + (size_t)(rowbase + wr * 4 + i) * NH
                               + wc * 1024 + l * 4;
        #pragma unroll
        for (int j = 0; j < 4; ++j)
            wreg[i][j] = *reinterpret_cast<const float4*>(wrow + j * 256);
    }
    if (tid < TPTS) tsh[tid] = t[tid];
    const float bias = (tid < 16) ? bf[rowbase + tid] : 0.f;
    __syncthreads();

// One RK4 sub-phase: stage v = HV + A*KV into LDS, dot all 16 rows, reduce,
// finalizer lanes (tid<16) run EPILOGUE with row sum s. Ends with grid.sync().
#define DO_PHASE(HV, KV, ACOEF, EPILOGUE)                                      \
    {                                                                          \
        const int idx = tid * 4;                                               \
        float4 hv = *reinterpret_cast<const float4*>((HV) + idx);              \
        float4 kv = *reinterpret_cast<const float4*>((KV) + idx);              \
        const float a_ = (ACOEF);                                              \
        vlds[idx + 0] = hv.x + a_ * kv.x;                                      \
        vlds[idx + 1] = hv.y + a_ * kv.y;                                      \
        vlds[idx + 2] = hv.z + a_ * kv.z;                                      \
        vlds[idx + 3] = hv.w + a_ * kv.w;                                      \
        __syncthreads();                                                       \
        float p0 = 0.f, p1 = 0.f, p2 = 0.f, p3 = 0.f;                          \
        _Pragma("unroll")                                                      \
        for (int j = 0; j < 4; ++j) {                                          \
            float4 v = *reinterpret_cast<const float4*>(                       \
                &vlds[wc * 1024 + j * 256 + l * 4]);                           \
            p0 += wreg[0][j].x*v.x + wreg[0][j].y*v.y                          \
                + wreg[0][j].z*v.z + wreg[0][j].w*v.w;                         \
            p1 += wreg[1][j].x*v.x + wreg[1][j].y*v.y                          \
                + wreg[1][j].z*v.z + wreg[1][j].w*v.w;                         \
            p2 += wreg[2][j].x*v.x + wreg[2][j].y*v.y                          \
                + wreg[2][j].z*v.z + wreg[2][j].w*v.w;                         \
            p3 += wreg[3][j].x*v.x + wreg[3][j].y*v.y                          \
                + wreg[3][j].z*v.z + wreg[3][j].w*v.w;                         \
        }                                                                      \
        _Pragma("unroll")                                                      \
        for (int off = 32; off > 0; off >>= 1) {                               \
            p0 += __shfl_down(p0, off);                                        \
            p1 += __shfl_down(p1, off);                                        \
            p2 += __shfl_down(p2, off);                                        \
            p3 += __shfl_down(p3, off);                                        \
        }                                                                      \
        if (l == 0) {                                                          \
            pLDS[wr * 4 + 0][wc] = p0;                                         \
            pLDS[wr * 4 + 1][wc] = p1;                                         \
            pLDS[wr * 4 + 2][wc] = p2;                                         \
            pLDS[wr * 4 + 3][wc] = p3;                                         \
        }                                                                      \
        __syncthreads();                                                       \
        if (tid < 16) {                                                        \
            float s = pLDS[tid][0] + pLDS[tid][1]                              \
                    + pLDS[tid][2] + pLDS[tid][3] + bias;                      \
            EPILOGUE;                                                          \
        }                                                                      \
        grid.sync();                                                           \
    }

    float* hcur = hA;
    float* hnxt = hB;
    for (int s = 0; s < TPTS - 1; ++s) {
        const float dt  = tsh[s + 1] - tsh[s];
        const float hdt = 0.5f * dt;
        const float dt6 = dt / 6.f;

        DO_PHASE(hcur, hcur, 0.f,  k1g[rowbase + tid] = tanhf(s));
        DO_PHASE(hcur, k1g,  hdt,  k2g[rowbase + tid] = tanhf(s));
        DO_PHASE(hcur, k2g,  hdt,  k3g[rowbase + tid] = tanhf(s));
        DO_PHASE(hcur, k3g,  dt,
            {
                float kk4 = tanhf(s);
                int r = rowbase + tid;
                hnxt[r] = hcur[r] + dt6 * (k1g[r] + 2.f * k2g[r]
                                           + 2.f * k3g[r] + kk4);
            });

        float* tmp = hcur; hcur = hnxt; hnxt = tmp;
    }
    // 63 steps (odd): final state lives in hB
#undef DO_PHASE
}

// ---------------- fallback f32 path (proven: 3531 us, passing) ---------------
__device__ __forceinline__ void stage_vec(float* vec, const float* __restrict__ h,
                                          const float* __restrict__ k, float a, int tid)
{
    if (k) {
        for (int i = tid * 4; i < NH; i += 1024) {
            float4 hv = *reinterpret_cast<const float4*>(h + i);
            float4 kv = *reinterpret_cast<const float4*>(k + i);
            vec[i + 0] = hv.x + a * kv.x;
            vec[i + 1] = hv.y + a * kv.y;
            vec[i + 2] = hv.z + a * kv.z;
            vec[i + 3] = hv.w + a * kv.w;
        }
    } else {
        for (int i = tid * 4; i < NH; i += 1024)
            *reinterpret_cast<float4*>(vec + i) =
                *reinterpret_cast<const float4*>(h + i);
    }
}

__global__ __launch_bounds__(256) void ode_eval(
    const float* __restrict__ Wf, const float* __restrict__ bf,
    const float* __restrict__ h, const float* __restrict__ k_in,
    const float* __restrict__ t, int step, float afrac,
    float* __restrict__ k_out)
{
    __shared__ float vec[NH];
    const int tid = threadIdx.x;
    const float dt = t[step + 1] - t[step];
    stage_vec(vec, h, k_in, afrac * dt, tid);
    __syncthreads();

    const int wave = tid >> 6, lane = tid & 63;
    const int row = blockIdx.x * 4 + wave;
    const float* wrow = Wf + (size_t)row * NH;
    float acc = 0.f;
    for (int c = lane * 4; c < NH; c += 256) {
        float4 wv = *reinterpret_cast<const float4*>(wrow + c);
        float4 v = *reinterpret_cast<const float4*>(vec + c);
        acc += wv.x * v.x + wv.y * v.y + wv.z * v.z + wv.w * v.w;
    }
    for (int o = 32; o > 0; o >>= 1) acc += __shfl_down(acc, o);
    if (lane == 0) k_out[row] = tanhf(acc + bf[row]);
}

__global__ __launch_bounds__(256) void ode_final(
    const float* __restrict__ Wf, const float* __restrict__ bf,
    const float* __restrict__ h, const float* __restrict__ k1,
    const float* __restrict__ k2, const float* __restrict__ k3,
    const float* __restrict__ t, int step,
    float* __restrict__ h_out)
{
    __shared__ float vec[NH];
    const int tid = threadIdx.x;
    const float dt = t[step + 1] - t[step];
    stage_vec(vec, h, k3, dt, tid);
    __syncthreads();

    const int wave = tid >> 6, lane = tid & 63;
    const int row = blockIdx.x * 4 + wave;
    const float* wrow = Wf + (size_t)row * NH;
    float acc = 0.f;
    for (int c = lane * 4; c < NH; c += 256) {
        float4 wv = *reinterpret_cast<const float4*>(wrow + c);
        float4 v = *reinterpret_cast<const float4*>(vec + c);
        acc += wv.x * v.x + wv.y * v.y + wv.z * v.z + wv.w * v.w;
    }
    for (int o = 32; o > 0; o >>= 1) acc += __shfl_down(acc, o);
    if (lane == 0) {
        float k4 = tanhf(acc + bf[row]);
        h_out[row] = h[row] + (dt / 6.f) *
                     (k1[row] + 2.f * k2[row] + 2.f * k3[row] + k4);
    }
}

// ---------------- head kernels ----------------------------------------------
__global__ __launch_bounds__(256) void i2h_kernel(
    const float* __restrict__ W, const float* __restrict__ b,
    const float* __restrict__ x, const float* __restrict__ hT,
    float* __restrict__ out)
{
    __shared__ float vec[COMB];
    const int tid = threadIdx.x;
    for (int i = tid * 4; i < COMB; i += 1024) {
        float4 v;
        if (i < OBS) v = *reinterpret_cast<const float4*>(x + i);
        else         v = *reinterpret_cast<const float4*>(hT + (i - OBS));
        *reinterpret_cast<float4*>(vec + i) = v;
    }
    __syncthreads();

    const int wave = tid >> 6, lane = tid & 63;
    const int row = blockIdx.x * 4 + wave;
    const float* wrow = W + (size_t)row * COMB;
    float acc = 0.f;
    for (int c = lane * 4; c < COMB; c += 256) {
        float4 wv = *reinterpret_cast<const float4*>(wrow + c);
        float4 v = *reinterpret_cast<const float4*>(vec + c);
        acc += wv.x * v.x + wv.y * v.y + wv.z * v.z + wv.w * v.w;
    }
    for (int o = 32; o > 0; o >>= 1) acc += __shfl_down(acc, o);
    if (lane == 0) out[row] = tanhf(acc + b[row]);
}

__global__ __launch_bounds__(256) void h2o_kernel(
    const float* __restrict__ W, const float* __restrict__ b,
    const float* __restrict__ hn, float* __restrict__ out)
{
    __shared__ float vec[NH];
    const int tid = threadIdx.x;
    for (int i = tid * 4; i < NH; i += 1024)
        *reinterpret_cast<float4*>(vec + i) =
            *reinterpret_cast<const float4*>(hn + i);
    __syncthreads();

    const int wave = tid >> 6, lane = tid & 63;
    const int row = blockIdx.x * 4 + wave;
    const float* wrow = W + (size_t)row * NH;
    float acc = 0.f;
    for (int c = lane * 4; c < NH; c += 256) {
        float4 wv = *reinterpret_cast<const float4*>(wrow + c);
        float4 v = *reinterpret_cast<const float4*>(vec + c);
        acc += wv.x * v.x + wv.y * v.y + wv.z * v.z + wv.w * v.w;
    }
    for (int o = 32; o > 0; o >>= 1) acc += __shfl_down(acc, o);
    if (lane == 0) out[row] = acc + b[row];
}

extern "C" void kernel_launch(void* const* d_in, const int* in_sizes, int n_in,
                              void* d_out, int out_size, void* d_ws, size_t ws_size,
                              hipStream_t stream)
{
    const float* x     = (const float*)d_in[0];
    const float* h0    = (const float*)d_in[1];
    const float* t     = (const float*)d_in[2];
    const float* Wf    = (const float*)d_in[3];
    const float* bf    = (const float*)d_in[4];
    const float* W_i2h = (const float*)d_in[5];
    const float* b_i2h = (const float*)d_in[6];
    const float* W_h2o = (const float*)d_in[7];
    const float* b_h2o = (const float*)d_in[8];
    float* out = (float*)d_out;

    float* ws = (float*)d_ws;
    float* hA = ws;
    float* hB = ws + NH;
    float* k1 = ws + 2 * NH;
    float* k2 = ws + 3 * NH;
    float* k3 = ws + 4 * NH;

    hipMemcpyAsync(hA, h0, NH * sizeof(float), hipMemcpyDeviceToDevice, stream);

    // ---- persistent cooperative path: Wf register-resident, f32 exact ----
    void* kargs[] = {(void*)&Wf, (void*)&bf, (void*)&t,
                     (void*)&hA, (void*)&hB, (void*)&k1, (void*)&k2, (void*)&k3};
    hipError_t rc = hipLaunchCooperativeKernel((void*)ode_resident,
                                               dim3(256), dim3(1024),
                                               kargs, 0, stream);
    float* hT = hB;  // 63 steps (odd) -> final state in hB

    if (rc != hipSuccess) {
        // ---- deterministic fallback: proven f32 multi-dispatch path ----
        float* hcur = hA;
        float* hnxt = hB;
        const int grid = NH / 4;
        for (int s = 0; s < TPTS - 1; ++s) {
            ode_eval<<<grid, 256, 0, stream>>>(Wf, bf, hcur, nullptr, t, s, 0.0f, k1);
            ode_eval<<<grid, 256, 0, stream>>>(Wf, bf, hcur, k1,      t, s, 0.5f, k2);
            ode_eval<<<grid, 256, 0, stream>>>(Wf, bf, hcur, k2,      t, s, 0.5f, k3);
            ode_final<<<grid, 256, 0, stream>>>(Wf, bf, hcur, k1, k2, k3, t, s, hnxt);
            float* tmp = hcur; hcur = hnxt; hnxt = tmp;
        }
        hT = hcur;
    }

    i2h_kernel<<<NH / 4, 256, 0, stream>>>(W_i2h, b_i2h, x, hT, out + LAT2);
    h2o_kernel<<<LAT2 / 4, 256, 0, stream>>>(W_h2o, b_h2o, out + LAT2, out);
}

// Round 6
// 1227.833 us; speedup vs baseline: 6.1143x; 6.1143x over previous
//
#include <hip/hip_runtime.h>

#define NH   4096
#define OBS  512
#define TPTS 64
#define LAT2 128
#define COMB (OBS + NH)
#define NBLK 256
#define NLEAF 16
#define BLK_PER_LEAF (NBLK / NLEAF)
#define BAR_WORDS (NLEAF * 64 + 128)   // leaf counters (256B apart) + root + release

typedef float f32x4 __attribute__((ext_vector_type(4)));

// ---- L2-bypassing (device-coherent) 16B load / 4B store: no fences needed ---
__device__ __forceinline__ f32x4 ld_dev16(const float* p) {
    f32x4 v;
    asm volatile("global_load_dwordx4 %0, %1, off sc0 sc1\n\ts_waitcnt vmcnt(0)"
                 : "=v"(v) : "v"(p) : "memory");
    return v;
}
__device__ __forceinline__ void st_dev4(float* p, float v) {
    asm volatile("global_store_dword %0, %1, off sc0 sc1"
                 :: "v"(p), "v"(v) : "memory");
}

// ---- hierarchical fence-free grid barrier (monotonic epochs) ----------------
// Data visibility: all cross-block data uses sc0sc1 ops; wave 0 does
// s_waitcnt vmcnt(0) before arrival, so stores are device-visible at release.
__device__ __forceinline__ void grid_barrier(unsigned* bar, unsigned epoch, int bid)
{
    __syncthreads();
    if (threadIdx.x == 0) {
        asm volatile("s_waitcnt vmcnt(0)" ::: "memory");
        unsigned* leaf = bar + (bid & (NLEAF - 1)) * 64;
        unsigned prev = __hip_atomic_fetch_add(leaf, 1u, __ATOMIC_RELAXED,
                                               __HIP_MEMORY_SCOPE_AGENT);
        if ((prev & (BLK_PER_LEAF - 1)) == BLK_PER_LEAF - 1) {
            unsigned* root = bar + NLEAF * 64;
            unsigned rprev = __hip_atomic_fetch_add(root, 1u, __ATOMIC_RELAXED,
                                                    __HIP_MEMORY_SCOPE_AGENT);
            if ((rprev & (NLEAF - 1)) == NLEAF - 1)
                __hip_atomic_store(bar + NLEAF * 64 + 64, epoch,
                                   __ATOMIC_RELAXED, __HIP_MEMORY_SCOPE_AGENT);
        }
        while (__hip_atomic_load(bar + NLEAF * 64 + 64, __ATOMIC_RELAXED,
                                 __HIP_MEMORY_SCOPE_AGENT) < epoch)
            __builtin_amdgcn_s_sleep(1);
    }
    __syncthreads();
}

__global__ __launch_bounds__(256) void bar_init(unsigned* bar)
{
    for (int i = threadIdx.x; i < BAR_WORDS; i += 256) bar[i] = 0u;
}

// ============================================================================
// Persistent RK4, Wf register-resident (64 VGPRs/lane of weights).
// 256 blocks x 1024 threads, 1 block/CU. Block b owns rows b*16..b*16+15.
// Wave w=(wr,wc): 4 rows x 1024-col quarter. Custom barrier, no cg.
// ============================================================================
__global__ __launch_bounds__(1024, 4) void ode_resident(
    const float* __restrict__ Wf, const float* __restrict__ bf,
    const float* __restrict__ t,
    float* hA, float* hB, float* k1g, float* k2g, float* k3g,
    unsigned* bar)
{
    __shared__ float hlds[NH];        // current h (staged once per step)
    __shared__ float vlds[NH];        // matvec input vector
    __shared__ float pLDS[16][4];     // cross-wave partials [row][wc]
    __shared__ float tsh[TPTS];
    __shared__ float kslice[3][16];   // this block's rows of k1,k2,k3

    const int tid = threadIdx.x;
    const int l   = tid & 63;
    const int w   = tid >> 6;
    const int wr  = w >> 2;
    const int wc  = w & 3;
    const int bid = blockIdx.x;
    const int rowbase = bid * 16;
    const int idx = tid * 4;

    // ---- one-time: weights into VGPRs (all statically indexed) ----
    float4 wreg[4][4];
    #pragma unroll
    for (int i = 0; i < 4; ++i) {
        const float* wrow = Wf + (size_t)(rowbase + wr * 4 + i) * NH
                               + wc * 1024 + l * 4;
        #pragma unroll
        for (int j = 0; j < 4; ++j)
            wreg[i][j] = *reinterpret_cast<const float4*>(wrow + j * 256);
    }
    if (tid < TPTS) tsh[tid] = t[tid];
    const float bias = (tid < 16) ? bf[rowbase + tid] : 0.f;
    __syncthreads();

#define DOT_REDUCE()                                                           \
    float p0 = 0.f, p1 = 0.f, p2 = 0.f, p3 = 0.f;                              \
    _Pragma("unroll")                                                          \
    for (int j = 0; j < 4; ++j) {                                              \
        f32x4 v = *(const f32x4*)&vlds[wc * 1024 + j * 256 + l * 4];           \
        p0 += wreg[0][j].x*v.x + wreg[0][j].y*v.y                              \
            + wreg[0][j].z*v.z + wreg[0][j].w*v.w;                             \
        p1 += wreg[1][j].x*v.x + wreg[1][j].y*v.y                              \
            + wreg[1][j].z*v.z + wreg[1][j].w*v.w;                             \
        p2 += wreg[2][j].x*v.x + wreg[2][j].y*v.y                              \
            + wreg[2][j].z*v.z + wreg[2][j].w*v.w;                             \
        p3 += wreg[3][j].x*v.x + wreg[3][j].y*v.y                              \
            + wreg[3][j].z*v.z + wreg[3][j].w*v.w;                             \
    }                                                                          \
    _Pragma("unroll")                                                          \
    for (int off = 32; off > 0; off >>= 1) {                                   \
        p0 += __shfl_down(p0, off); p1 += __shfl_down(p1, off);                \
        p2 += __shfl_down(p2, off); p3 += __shfl_down(p3, off);                \
    }                                                                          \
    if (l == 0) {                                                              \
        pLDS[wr * 4 + 0][wc] = p0; pLDS[wr * 4 + 1][wc] = p1;                  \
        pLDS[wr * 4 + 2][wc] = p2; pLDS[wr * 4 + 3][wc] = p3;                  \
    }                                                                          \
    __syncthreads();

#define ROWSUM() (pLDS[tid][0] + pLDS[tid][1] + pLDS[tid][2] + pLDS[tid][3] + bias)

    unsigned epoch = 0;
    float* hcur = hA;
    float* hnxt = hB;

    for (int s = 0; s < TPTS - 1; ++s) {
        const float dt  = tsh[s + 1] - tsh[s];
        const float hdt = 0.5f * dt;
        const float dt6 = dt / 6.f;

        // ---- phase 1: v = h ; k1 = tanh(Wv + b) ----
        {
            f32x4 hv = ld_dev16(hcur + idx);
            *(f32x4*)&hlds[idx] = hv;
            *(f32x4*)&vlds[idx] = hv;
            __syncthreads();
            DOT_REDUCE();
            if (tid < 16) st_dev4(k1g + rowbase + tid, tanhf(ROWSUM()));
            grid_barrier(bar, ++epoch, bid);
        }
        // ---- phase 2: v = h + dt/2 k1 ; k2 ----
        {
            f32x4 kv = ld_dev16(k1g + idx);
            int soff = idx - rowbase;
            if ((unsigned)soff < 16u) {
                kslice[0][soff] = kv.x; kslice[0][soff+1] = kv.y;
                kslice[0][soff+2] = kv.z; kslice[0][soff+3] = kv.w;
            }
            f32x4 hv = *(const f32x4*)&hlds[idx];
            f32x4 nv = { hv.x + hdt*kv.x, hv.y + hdt*kv.y,
                         hv.z + hdt*kv.z, hv.w + hdt*kv.w };
            *(f32x4*)&vlds[idx] = nv;
            __syncthreads();
            DOT_REDUCE();
            if (tid < 16) st_dev4(k2g + rowbase + tid, tanhf(ROWSUM()));
            grid_barrier(bar, ++epoch, bid);
        }
        // ---- phase 3: v = h + dt/2 k2 ; k3 ----
        {
            f32x4 kv = ld_dev16(k2g + idx);
            int soff = idx - rowbase;
            if ((unsigned)soff < 16u) {
                kslice[1][soff] = kv.x; kslice[1][soff+1] = kv.y;
                kslice[1][soff+2] = kv.z; kslice[1][soff+3] = kv.w;
            }
            f32x4 hv = *(const f32x4*)&hlds[idx];
            f32x4 nv = { hv.x + hdt*kv.x, hv.y + hdt*kv.y,
                         hv.z + hdt*kv.z, hv.w + hdt*kv.w };
            *(f32x4*)&vlds[idx] = nv;
            __syncthreads();
            DOT_REDUCE();
            if (tid < 16) st_dev4(k3g + rowbase + tid, tanhf(ROWSUM()));
            grid_barrier(bar, ++epoch, bid);
        }
        // ---- phase 4: v = h + dt k3 ; k4 ; h update ----
        {
            f32x4 kv = ld_dev16(k3g + idx);
            int soff = idx - rowbase;
            if ((unsigned)soff < 16u) {
                kslice[2][soff] = kv.x; kslice[2][soff+1] = kv.y;
                kslice[2][soff+2] = kv.z; kslice[2][soff+3] = kv.w;
            }
            f32x4 hv = *(const f32x4*)&hlds[idx];
            f32x4 nv = { hv.x + dt*kv.x, hv.y + dt*kv.y,
                         hv.z + dt*kv.z, hv.w + dt*kv.w };
            *(f32x4*)&vlds[idx] = nv;
            __syncthreads();
            DOT_REDUCE();
            if (tid < 16) {
                float k4 = tanhf(ROWSUM());
                float hnew = hlds[rowbase + tid] + dt6 *
                    (kslice[0][tid] + 2.f * kslice[1][tid]
                     + 2.f * kslice[2][tid] + k4);
                st_dev4(hnxt + rowbase + tid, hnew);
            }
            grid_barrier(bar, ++epoch, bid);
        }
        float* tmp = hcur; hcur = hnxt; hnxt = tmp;
    }
    // 63 steps (odd): final state lives in hB
#undef DOT_REDUCE
#undef ROWSUM
}

// ---------------- fallback f32 path (proven: 3531 us, passing) ---------------
__device__ __forceinline__ void stage_vec(float* vec, const float* __restrict__ h,
                                          const float* __restrict__ k, float a, int tid)
{
    if (k) {
        for (int i = tid * 4; i < NH; i += 1024) {
            float4 hv = *reinterpret_cast<const float4*>(h + i);
            float4 kv = *reinterpret_cast<const float4*>(k + i);
            vec[i + 0] = hv.x + a * kv.x;
            vec[i + 1] = hv.y + a * kv.y;
            vec[i + 2] = hv.z + a * kv.z;
            vec[i + 3] = hv.w + a * kv.w;
        }
    } else {
        for (int i = tid * 4; i < NH; i += 1024)
            *reinterpret_cast<float4*>(vec + i) =
                *reinterpret_cast<const float4*>(h + i);
    }
}

__global__ __launch_bounds__(256) void ode_eval(
    const float* __restrict__ Wf, const float* __restrict__ bf,
    const float* __restrict__ h, const float* __restrict__ k_in,
    const float* __restrict__ t, int step, float afrac,
    float* __restrict__ k_out)
{
    __shared__ float vec[NH];
    const int tid = threadIdx.x;
    const float dt = t[step + 1] - t[step];
    stage_vec(vec, h, k_in, afrac * dt, tid);
    __syncthreads();

    const int wave = tid >> 6, lane = tid & 63;
    const int row = blockIdx.x * 4 + wave;
    const float* wrow = Wf + (size_t)row * NH;
    float acc = 0.f;
    for (int c = lane * 4; c < NH; c += 256) {
        float4 wv = *reinterpret_cast<const float4*>(wrow + c);
        float4 v = *reinterpret_cast<const float4*>(vec + c);
        acc += wv.x * v.x + wv.y * v.y + wv.z * v.z + wv.w * v.w;
    }
    for (int o = 32; o > 0; o >>= 1) acc += __shfl_down(acc, o);
    if (lane == 0) k_out[row] = tanhf(acc + bf[row]);
}

__global__ __launch_bounds__(256) void ode_final(
    const float* __restrict__ Wf, const float* __restrict__ bf,
    const float* __restrict__ h, const float* __restrict__ k1,
    const float* __restrict__ k2, const float* __restrict__ k3,
    const float* __restrict__ t, int step,
    float* __restrict__ h_out)
{
    __shared__ float vec[NH];
    const int tid = threadIdx.x;
    const float dt = t[step + 1] - t[step];
    stage_vec(vec, h, k3, dt, tid);
    __syncthreads();

    const int wave = tid >> 6, lane = tid & 63;
    const int row = blockIdx.x * 4 + wave;
    const float* wrow = Wf + (size_t)row * NH;
    float acc = 0.f;
    for (int c = lane * 4; c < NH; c += 256) {
        float4 wv = *reinterpret_cast<const float4*>(wrow + c);
        float4 v = *reinterpret_cast<const float4*>(vec + c);
        acc += wv.x * v.x + wv.y * v.y + wv.z * v.z + wv.w * v.w;
    }
    for (int o = 32; o > 0; o >>= 1) acc += __shfl_down(acc, o);
    if (lane == 0) {
        float k4 = tanhf(acc + bf[row]);
        h_out[row] = h[row] + (dt / 6.f) *
                     (k1[row] + 2.f * k2[row] + 2.f * k3[row] + k4);
    }
}

// ---------------- head kernels ----------------------------------------------
__global__ __launch_bounds__(256) void i2h_kernel(
    const float* __restrict__ W, const float* __restrict__ b,
    const float* __restrict__ x, const float* __restrict__ hT,
    float* __restrict__ out)
{
    __shared__ float vec[COMB];
    const int tid = threadIdx.x;
    for (int i = tid * 4; i < COMB; i += 1024) {
        float4 v;
        if (i < OBS) v = *reinterpret_cast<const float4*>(x + i);
        else         v = *reinterpret_cast<const float4*>(hT + (i - OBS));
        *reinterpret_cast<float4*>(vec + i) = v;
    }
    __syncthreads();

    const int wave = tid >> 6, lane = tid & 63;
    const int row = blockIdx.x * 4 + wave;
    const float* wrow = W + (size_t)row * COMB;
    float acc = 0.f;
    for (int c = lane * 4; c < COMB; c += 256) {
        float4 wv = *reinterpret_cast<const float4*>(wrow + c);
        float4 v = *reinterpret_cast<const float4*>(vec + c);
        acc += wv.x * v.x + wv.y * v.y + wv.z * v.z + wv.w * v.w;
    }
    for (int o = 32; o > 0; o >>= 1) acc += __shfl_down(acc, o);
    if (lane == 0) out[row] = tanhf(acc + b[row]);
}

__global__ __launch_bounds__(256) void h2o_kernel(
    const float* __restrict__ W, const float* __restrict__ b,
    const float* __restrict__ hn, float* __restrict__ out)
{
    __shared__ float vec[NH];
    const int tid = threadIdx.x;
    for (int i = tid * 4; i < NH; i += 1024)
        *reinterpret_cast<float4*>(vec + i) =
            *reinterpret_cast<const float4*>(hn + i);
    __syncthreads();

    const int wave = tid >> 6, lane = tid & 63;
    const int row = blockIdx.x * 4 + wave;
    const float* wrow = W + (size_t)row * NH;
    float acc = 0.f;
    for (int c = lane * 4; c < NH; c += 256) {
        float4 wv = *reinterpret_cast<const float4*>(wrow + c);
        float4 v = *reinterpret_cast<const float4*>(vec + c);
        acc += wv.x * v.x + wv.y * v.y + wv.z * v.z + wv.w * v.w;
    }
    for (int o = 32; o > 0; o >>= 1) acc += __shfl_down(acc, o);
    if (lane == 0) out[row] = acc + b[row];
}

extern "C" void kernel_launch(void* const* d_in, const int* in_sizes, int n_in,
                              void* d_out, int out_size, void* d_ws, size_t ws_size,
                              hipStream_t stream)
{
    const float* x     = (const float*)d_in[0];
    const float* h0    = (const float*)d_in[1];
    const float* t     = (const float*)d_in[2];
    const float* Wf    = (const float*)d_in[3];
    const float* bf    = (const float*)d_in[4];
    const float* W_i2h = (const float*)d_in[5];
    const float* b_i2h = (const float*)d_in[6];
    const float* W_h2o = (const float*)d_in[7];
    const float* b_h2o = (const float*)d_in[8];
    float* out = (float*)d_out;

    float* ws = (float*)d_ws;
    float* hA = ws;
    float* hB = ws + NH;
    float* k1 = ws + 2 * NH;
    float* k2 = ws + 3 * NH;
    float* k3 = ws + 4 * NH;
    unsigned* bar = (unsigned*)(ws + 5 * NH);

    hipMemcpyAsync(hA, h0, NH * sizeof(float), hipMemcpyDeviceToDevice, stream);
    bar_init<<<1, 256, 0, stream>>>(bar);

    // ---- persistent path: Wf register-resident, custom fence-free barrier ----
    void* kargs[] = {(void*)&Wf, (void*)&bf, (void*)&t,
                     (void*)&hA, (void*)&hB, (void*)&k1, (void*)&k2, (void*)&k3,
                     (void*)&bar};
    hipError_t rc = hipLaunchCooperativeKernel((void*)ode_resident,
                                               dim3(NBLK), dim3(1024),
                                               kargs, 0, stream);
    float* hT = hB;  // 63 steps (odd) -> final state in hB

    if (rc != hipSuccess) {
        // ---- deterministic fallback: proven f32 multi-dispatch path ----
        float* hcur = hA;
        float* hnxt = hB;
        const int grid = NH / 4;
        for (int s = 0; s < TPTS - 1; ++s) {
            ode_eval<<<grid, 256, 0, stream>>>(Wf, bf, hcur, nullptr, t, s, 0.0f, k1);
            ode_eval<<<grid, 256, 0, stream>>>(Wf, bf, hcur, k1,      t, s, 0.5f, k2);
            ode_eval<<<grid, 256, 0, stream>>>(Wf, bf, hcur, k2,      t, s, 0.5f, k3);
            ode_final<<<grid, 256, 0, stream>>>(Wf, bf, hcur, k1, k2, k3, t, s, hnxt);
            float* tmp = hcur; hcur = hnxt; hnxt = tmp;
        }
        hT = hcur;
    }

    i2h_kernel<<<NH / 4, 256, 0, stream>>>(W_i2h, b_i2h, x, hT, out + LAT2);
    h2o_kernel<<<LAT2 / 4, 256, 0, stream>>>(W_h2o, b_h2o, out + LAT2, out);
}